// Round 3
// baseline (350.436 us; speedup 1.0000x reference)
//
#include <hip/hip_runtime.h>
#include <math.h>

#define GRAPHS 8192
#define M 64
#define KNBR 32
#define NK (GRAPHS * M * KNBR)   // 16,777,216 edges

// One block per graph (256 threads = 4 waves); each wave owns 16 nodes,
// processed in 4 groups of 4. Per group, 4 independent 64-lane bitonic sort
// chains are interleaved stage-by-stage for ILP (hides ds_swizzle latency).
// Key = (sq_bits & ~63) | candidate_lane  -> ascending sort == top_k order
// with smaller-index tie-break (matches jax.lax.top_k stability).
// Epilogue packs two nodes' sorted K=32 across the full 64-lane wave so every
// store is a contiguous 256 B nontemporal write.
__global__ __launch_bounds__(256) void radius_graph_kernel(
    const float* __restrict__ pos, float* __restrict__ out) {
#pragma clang fp contract(off)
  __shared__ float sx[M], sy[M], sz[M], sn2[M];

  const int g    = blockIdx.x;
  const int tid  = threadIdx.x;
  const int lane = tid & 63;
  const int wave = tid >> 6;
  const int base = g * M;

  if (tid < M) {
    float x = pos[(size_t)(base + tid) * 3 + 0];
    float y = pos[(size_t)(base + tid) * 3 + 1];
    float z = pos[(size_t)(base + tid) * 3 + 2];
    sx[tid] = x; sy[tid] = y; sz[tid] = z;
    sn2[tid] = (x * x + y * y) + z * z;   // plain ops, np sum order
  }
  __syncthreads();

  // candidate j = lane, loop-invariant
  const float xj = sx[lane], yj = sy[lane], zj = sz[lane], n2j = sn2[lane];

  for (int tq = 0; tq < 4; ++tq) {
    const int i0 = wave * 16 + tq * 4;

    unsigned key[4];
    #pragma unroll
    for (int c = 0; c < 4; ++c) {
      const int i = i0 + c;
      const float xi = sx[i], yi = sy[i], zi = sz[i], n2i = sn2[i];
      float gd = __builtin_fmaf(zi, zj, __builtin_fmaf(yi, yj, xi * xj));
      float sq = fmaxf((n2i + n2j) - 2.0f * gd, 0.0f);
      unsigned kb = __float_as_uint(sq);
      // self -> above any real key (max finite sq ~3.0 -> bits ~0x40400000);
      // 0x7FFFFFC0 keeps the sign bit clear (signed/unsigned compare agree)
      key[c] = (lane == i) ? (0x7FFFFFC0u | (unsigned)lane)
                           : ((kb & 0xFFFFFFC0u) | (unsigned)lane);
    }

    // 4 interleaved 64-lane bitonic sorts, ascending
    #pragma unroll
    for (int kk = 2; kk <= 64; kk <<= 1) {
      #pragma unroll
      for (int j = kk >> 1; j > 0; j >>= 1) {
        const bool dir = (((lane & kk) == 0) == ((lane & j) == 0)); // keep-min?
        #pragma unroll
        for (int c = 0; c < 4; ++c) {
          unsigned o = (unsigned)__shfl_xor((int)key[c], j, 64);
          bool lt = key[c] < o;
          key[c] = (lt == dir) ? key[c] : o;
        }
      }
    }

    // epilogue: pairs (0,1), (2,3) -> full-wave contiguous stores
    #pragma unroll
    for (int p = 0; p < 2; ++p) {
      unsigned kA = key[2 * p], kB = key[2 * p + 1];
      unsigned kBsw = (unsigned)__shfl_xor((int)kB, 32, 64);
      unsigned k = (lane < 32) ? kA : kBsw;

      const int i = i0 + 2 * p + (lane >> 5);    // node for this lane
      const int nb = (int)(k & 63u);

      const float xi = sx[i],  yi = sy[i],  zi = sz[i],  n2i = sn2[i];
      const float xn = sx[nb], yn = sy[nb], zn = sz[nb], n2n = sn2[nb];

      // exact gram sq for the valid decision (same expr as key-gen)
      float gde = __builtin_fmaf(zi, zn, __builtin_fmaf(yi, yn, xi * xn));
      float sqe = fmaxf((n2i + n2n) - 2.0f * gde, 0.0f);
      bool valid = (sqe <= 0.25f);

      int tgt = base + i;
      int src = valid ? (base + nb) : tgt;

      float dx = xn - xi, dy = yn - yi, dz = zn - zi;
      float w  = valid ? sqrtf((dx * dx + dy * dy) + dz * dz) : 0.0f;

      size_t e = (size_t)tgt * KNBR + (size_t)(lane & 31);
      __builtin_nontemporal_store((float)src, &out[e]);
      __builtin_nontemporal_store((float)tgt, &out[(size_t)NK + e]);
      __builtin_nontemporal_store(w,          &out[2 * (size_t)NK + e]);
      __builtin_nontemporal_store(valid ? 1.0f : 0.0f, &out[3 * (size_t)NK + e]);
    }
  }
}

extern "C" void kernel_launch(void* const* d_in, const int* in_sizes, int n_in,
                              void* d_out, int out_size, void* d_ws, size_t ws_size,
                              hipStream_t stream) {
  const float* pos = (const float*)d_in[0];
  // d_in[1] (batch) unused: graphs are equal-size (M=64)
  float* out = (float*)d_out;
  radius_graph_kernel<<<GRAPHS, 256, 0, stream>>>(pos, out);
}

// Round 4
// 300.705 us; speedup vs baseline: 1.1654x; 1.1654x over previous
//
#include <hip/hip_runtime.h>
#include <math.h>

#define GRAPHS 8192
#define M 64
#define KNBR 32
#define NK (GRAPHS * M * KNBR)   // 16,777,216 edges

// One block per graph (256 threads = 4 waves); each wave owns 16 nodes,
// processed in 4 groups of 4 interleaved sort chains (ILP).
// Bitonic 64-lane sort with cross-lane moves on the VALU (DPP) wherever the
// stride permits; only xor16/xor32 touch the DS pipe (ds_bpermute). This cuts
// DS-pipe ops per node from 21 to 3 — R3 showed the kernel is DS-throughput
// bound (ILP restructure was a perfect null).
// Key = (sq_bits & ~63) | candidate_lane -> ascending sort == top_k order
// with smaller-index tie-break (matches jax.lax.top_k stability).

template <int J>
__device__ __forceinline__ unsigned lane_xor(unsigned x) {
  if constexpr (J == 1) {        // quad_perm [1,0,3,2]
    return (unsigned)__builtin_amdgcn_update_dpp((int)x, (int)x, 0xB1, 0xF, 0xF, false);
  } else if constexpr (J == 2) { // quad_perm [2,3,0,1]
    return (unsigned)__builtin_amdgcn_update_dpp((int)x, (int)x, 0x4E, 0xF, 0xF, false);
  } else if constexpr (J == 4) { // row_half_mirror (^7) then quad mirror (^3)
    int t = __builtin_amdgcn_update_dpp((int)x, (int)x, 0x141, 0xF, 0xF, false);
    return (unsigned)__builtin_amdgcn_update_dpp(t, t, 0x1B, 0xF, 0xF, false);
  } else if constexpr (J == 8) { // row_ror:8 == xor8 within 16-lane rows
    return (unsigned)__builtin_amdgcn_update_dpp((int)x, (int)x, 0x128, 0xF, 0xF, false);
  } else {                       // 16, 32: cross-row -> DS pipe
    return (unsigned)__shfl_xor((int)x, J, 64);
  }
}

__global__ __launch_bounds__(256) void radius_graph_kernel(
    const float* __restrict__ pos, float* __restrict__ out) {
#pragma clang fp contract(off)
  __shared__ float sx[M], sy[M], sz[M], sn2[M];

  const int g    = blockIdx.x;
  const int tid  = threadIdx.x;
  const int lane = tid & 63;
  const int wave = tid >> 6;
  const int base = g * M;

  if (tid < M) {
    float x = pos[(size_t)(base + tid) * 3 + 0];
    float y = pos[(size_t)(base + tid) * 3 + 1];
    float z = pos[(size_t)(base + tid) * 3 + 2];
    sx[tid] = x; sy[tid] = y; sz[tid] = z;
    sn2[tid] = (x * x + y * y) + z * z;   // plain ops, np sum order
  }
  __syncthreads();

  // candidate j = lane, loop-invariant
  const float xj = sx[lane], yj = sy[lane], zj = sz[lane], n2j = sn2[lane];

  for (int tq = 0; tq < 4; ++tq) {
    const int i0 = wave * 16 + tq * 4;

    unsigned key[4];
    #pragma unroll
    for (int c = 0; c < 4; ++c) {
      const int i = i0 + c;
      const float xi = sx[i], yi = sy[i], zi = sz[i], n2i = sn2[i];
      float gd = __builtin_fmaf(zi, zj, __builtin_fmaf(yi, yj, xi * xj));
      float sq = fmaxf((n2i + n2j) - 2.0f * gd, 0.0f);
      unsigned kb = __float_as_uint(sq);
      // self -> above any real key; sign bit clear so u/s compares agree
      key[c] = (lane == i) ? (0x7FFFFFC0u | (unsigned)lane)
                           : ((kb & 0xFFFFFFC0u) | (unsigned)lane);
    }

    // 4 interleaved 64-lane bitonic sorts, ascending
#define CMPX(KK, J)                                                     \
    {                                                                   \
      const bool dir = (((lane & (KK)) == 0) == ((lane & (J)) == 0));   \
      _Pragma("unroll")                                                 \
      for (int c = 0; c < 4; ++c) {                                     \
        unsigned o = lane_xor<J>(key[c]);                               \
        bool lt = key[c] < o;                                           \
        key[c] = (lt == dir) ? key[c] : o;                              \
      }                                                                 \
    }
    CMPX(2, 1)
    CMPX(4, 2)  CMPX(4, 1)
    CMPX(8, 4)  CMPX(8, 2)  CMPX(8, 1)
    CMPX(16, 8) CMPX(16, 4) CMPX(16, 2) CMPX(16, 1)
    CMPX(32, 16) CMPX(32, 8) CMPX(32, 4) CMPX(32, 2) CMPX(32, 1)
    CMPX(64, 32) CMPX(64, 16) CMPX(64, 8) CMPX(64, 4) CMPX(64, 2) CMPX(64, 1)
#undef CMPX

    // epilogue: pairs (0,1), (2,3) -> full-wave contiguous 256 B stores
    #pragma unroll
    for (int p = 0; p < 2; ++p) {
      unsigned kA = key[2 * p], kB = key[2 * p + 1];
      unsigned kBsw = (unsigned)__shfl_xor((int)kB, 32, 64);
      unsigned k = (lane < 32) ? kA : kBsw;

      const int i = i0 + 2 * p + (lane >> 5);    // node for this lane
      const int nb = (int)(k & 63u);

      const float xi = sx[i],  yi = sy[i],  zi = sz[i],  n2i = sn2[i];
      const float xn = sx[nb], yn = sy[nb], zn = sz[nb], n2n = sn2[nb];

      // exact gram sq for the valid decision (same expr as key-gen)
      float gde = __builtin_fmaf(zi, zn, __builtin_fmaf(yi, yn, xi * xn));
      float sqe = fmaxf((n2i + n2n) - 2.0f * gde, 0.0f);
      bool valid = (sqe <= 0.25f);

      int tgt = base + i;
      int src = valid ? (base + nb) : tgt;

      float dx = xn - xi, dy = yn - yi, dz = zn - zi;
      float w  = valid ? sqrtf((dx * dx + dy * dy) + dz * dz) : 0.0f;

      size_t e = (size_t)tgt * KNBR + (size_t)(lane & 31);
      __builtin_nontemporal_store((float)src, &out[e]);
      __builtin_nontemporal_store((float)tgt, &out[(size_t)NK + e]);
      __builtin_nontemporal_store(w,          &out[2 * (size_t)NK + e]);
      __builtin_nontemporal_store(valid ? 1.0f : 0.0f, &out[3 * (size_t)NK + e]);
    }
  }
}

extern "C" void kernel_launch(void* const* d_in, const int* in_sizes, int n_in,
                              void* d_out, int out_size, void* d_ws, size_t ws_size,
                              hipStream_t stream) {
  const float* pos = (const float*)d_in[0];
  // d_in[1] (batch) unused: graphs are equal-size (M=64)
  float* out = (float*)d_out;
  radius_graph_kernel<<<GRAPHS, 256, 0, stream>>>(pos, out);
}